// Round 8
// baseline (552.123 us; speedup 1.0000x reference)
//
#include <hip/hip_runtime.h>
#include <cstddef>

#define NN 50000
#define NE 800000
#define HCH 256     // H*C
#define MPAD 50048  // 391*128

typedef __attribute__((ext_vector_type(4))) float f32x4;
typedef __attribute__((ext_vector_type(8))) short s16x8;
typedef __attribute__((ext_vector_type(8))) unsigned short u16x8;
typedef unsigned int uint32;

__device__ inline float bf2f(unsigned short u) {
    return __uint_as_float(((unsigned int)u) << 16);
}
__device__ inline unsigned short f2bf(float f) {
    unsigned int x = __float_as_uint(f);
    x += 0x7FFFu + ((x >> 16) & 1u);   // round to nearest even
    return (unsigned short)(x >> 16);
}

// ---------------- CSR build ----------------
__global__ void k_hist(const int* __restrict__ dst, int* __restrict__ deg, int e) {
    int i = blockIdx.x * blockDim.x + threadIdx.x;
    if (i < e) atomicAdd(&deg[dst[i]], 1);
}

__global__ __launch_bounds__(1024) void k_scan_a(const int* __restrict__ deg,
                                                 int* __restrict__ incl,
                                                 int* __restrict__ btot, int n) {
    __shared__ int buf[1024];
    int t = threadIdx.x;
    int i = blockIdx.x * 1024 + t;
    int v = (i < n) ? deg[i] : 0;
    buf[t] = v;
    __syncthreads();
    #pragma unroll
    for (int s = 1; s < 1024; s <<= 1) {
        int tv = (t >= s) ? buf[t - s] : 0;
        __syncthreads();
        buf[t] += tv;
        __syncthreads();
    }
    if (i < n) incl[i] = buf[t];
    if (t == 1023) btot[blockIdx.x] = buf[1023];
}

// scan_c with inline exclusive scan of block totals (one wave does 49 adds)
__global__ __launch_bounds__(1024) void k_scan_c(const int* __restrict__ deg,
                                                 const int* __restrict__ incl,
                                                 const int* __restrict__ btot,
                                                 int* __restrict__ off,
                                                 int* __restrict__ cur, int n, int nb) {
    __shared__ int bsh;
    int t = threadIdx.x;
    if (t < 64) {
        int v = (t < nb && t < (int)blockIdx.x) ? btot[t] : 0;
        #pragma unroll
        for (int m = 1; m < 64; m <<= 1) v += __shfl_xor(v, m);
        if (t == 0) bsh = v;
    }
    __syncthreads();
    int bbase = bsh;
    int i = blockIdx.x * 1024 + t;
    if (i < n) {
        int inc = bbase + incl[i];
        off[i + 1] = inc;
        cur[i] = inc - deg[i];
    }
    if (i == 0) off[0] = 0;
}

__global__ void k_scatter(const int* __restrict__ src, const int* __restrict__ dst,
                          const float* __restrict__ attr, int* __restrict__ cur,
                          int2* __restrict__ csr, int e) {
    int i = blockIdx.x * blockDim.x + threadIdx.x;
    if (i < e) {
        int d = dst[i];
        int pos = atomicAdd(&cur[d], 1);
        csr[pos] = make_int2(src[i], __float_as_int(attr[i]));
    }
}

// ---------------- fused prep: weight pack + deg zero + layer-0 Gram ----------------
struct PackSrc { const float* w[9]; };
__global__ void k_prep(PackSrc ps, unsigned short* __restrict__ Bt,
                       unsigned short* __restrict__ W1t, int* __restrict__ deg,
                       const float* __restrict__ Wq, const float* __restrict__ bq,
                       const float* __restrict__ Wk, const float* __restrict__ bk,
                       const float* __restrict__ We, float* __restrict__ gram) {
    int b = blockIdx.x;
    if (b < 2176) {
        int i = b * 256 + threadIdx.x;
        if (i < 524288) {
            int mi = i >> 16;
            int elem = i & 65535;
            int n = elem >> 8, k = elem & 255;
            Bt[i] = f2bf(ps.w[mi][(size_t)k * 256 + n]);
        } else {
            int e = i - 524288;
            int n = e >> 8, k = e & 255;
            W1t[e] = f2bf(ps.w[8][(size_t)k * 128 + n]);
        }
    } else if (b < 2176 + 196) {
        int i = (b - 2176) * 256 + threadIdx.x;
        if (i < NN) deg[i] = 0;
    } else {
        int t = threadIdx.x;
        if (t < 48) {
            int h = t / 12, q = t % 12, i = q >> 2, j = q & 3;
            const float* a = (i < 2) ? Wq + i * HCH + h * 64 : bq + h * 64;
            const float* bb = (j == 0) ? Wk + h * 64
                            : (j == 1) ? Wk + HCH + h * 64
                            : (j == 2) ? bk + h * 64
                                       : We + h * 64;
            float s = 0.f;
            for (int c = 0; c < 64; ++c) s = fmaf(a[c], bb[c], s);
            gram[h * 16 + i * 4 + j] = s;
        }
    }
}

// ---------------- layer-0 fused aggregation (rank-2 closed form) ----------------
__global__ __launch_bounds__(256) void k_agg0(
    const float* __restrict__ x, const int* __restrict__ off,
    const int2* __restrict__ csr, const float* __restrict__ gram,
    const float* __restrict__ Wv, const float* __restrict__ bv,
    const float* __restrict__ We, const float* __restrict__ Wsk,
    const float* __restrict__ bsk,
    unsigned short* __restrict__ Ho, int nnodes) {
    int n = blockIdx.x * 8 + (threadIdx.x >> 5);
    if (n >= nnodes) return;
    int s = threadIdx.x & 31;
    float xd0 = x[n * 2], xd1 = x[n * 2 + 1];

    float t0[4], t1[4], t2[4], ta[4];
    #pragma unroll
    for (int h = 0; h < 4; ++h) {
        const float* g = gram + h * 16;
        t0[h] = (xd0 * g[0] + xd1 * g[4] + g[8])  * 0.125f;
        t1[h] = (xd0 * g[1] + xd1 * g[5] + g[9])  * 0.125f;
        t2[h] = (xd0 * g[2] + xd1 * g[6] + g[10]) * 0.125f;
        ta[h] = (xd0 * g[3] + xd1 * g[7] + g[11]) * 0.125f;
    }

    float S0[4] = {0,0,0,0}, S1[4] = {0,0,0,0}, S2[4] = {0,0,0,0}, SE[4] = {0,0,0,0};
    int e0 = off[n], e1 = off[n + 1];
    for (int e = e0 + s; e < e1; e += 32) {
        int2 ee = csr[e];
        float2 xs = ((const float2*)x)[ee.x];
        float attr = __int_as_float(ee.y);
        #pragma unroll
        for (int h = 0; h < 4; ++h) {
            float alpha = fmaf(t0[h], xs.x, fmaf(t1[h], xs.y, fmaf(ta[h], attr, t2[h])));
            float w = __expf(fminf(alpha, 60.f));
            S0[h] = fmaf(w, xs.x, S0[h]);
            S1[h] = fmaf(w, xs.y, S1[h]);
            S2[h] += w;
            SE[h] = fmaf(w, attr, SE[h]);
        }
    }
    #pragma unroll
    for (int m = 1; m < 32; m <<= 1) {
        #pragma unroll
        for (int h = 0; h < 4; ++h) {
            S0[h] += __shfl_xor(S0[h], m);
            S1[h] += __shfl_xor(S1[h], m);
            S2[h] += __shfl_xor(S2[h], m);
            SE[h] += __shfl_xor(SE[h], m);
        }
    }
    int hs = s >> 3;
    float inv = 1.f / (S2[hs] + 1e-16f);
    float s0 = S0[hs], s1 = S1[hs], s2 = S2[hs], se = SE[hs];
    int cbase = s * 8;
    u16x8 o;
    #pragma unroll
    for (int c = 0; c < 8; ++c) {
        int ch = cbase + c;
        float msg = (s0 * Wv[ch] + s1 * Wv[HCH + ch] + s2 * bv[ch] + se * We[ch]) * inv;
        float val = msg + xd0 * Wsk[ch] + xd1 * Wsk[HCH + ch] + bsk[ch];
        o[c] = f2bf(fmaxf(val, 0.f));
    }
    *(u16x8*)(Ho + (size_t)n * HCH + cbase) = o;
}

// ---------------- unified 4-matrix MFMA GEMM, 2-phase LDS double-buffer ----------------
struct GOut4 {
    unsigned short* o[4];
    const float* b[4];
};

__global__ __launch_bounds__(256) void k_mfma4(
    const unsigned short* __restrict__ A, const unsigned short* __restrict__ Bt,
    GOut4 g, int M) {
    __shared__ __align__(16) unsigned short As[2][128 * 32];
    __shared__ __align__(16) unsigned short Bs[2][128 * 32];
    const int t = threadIdx.x, wid = t >> 6, l = t & 63;
    const int v = (blockIdx.x & 7) * 391 + (blockIdx.x >> 3);
    const int m0 = (v >> 3) * 128;
    const int n0 = (v & 7) * 128;
    const int wr = wid >> 1, wc = wid & 1;

    f32x4 acc[4][4];
    #pragma unroll
    for (int m = 0; m < 4; ++m)
        #pragma unroll
        for (int n = 0; n < 4; ++n) acc[m][n] = (f32x4)0.f;

    const int off0 = (wid * 2 + 0) * 1024 + l * 16;
    const int off1 = (wid * 2 + 1) * 1024 + l * 16;
    const int ar0 = off0 >> 6, ac0 = off0 & 63;
    const int ar1 = off1 >> 6, ac1 = off1 & 63;
    const char* Abase = (const char*)A;
    const char* Bbase = (const char*)Bt;
    char* AsB = (char*)As;
    char* BsB = (char*)Bs;

    auto STAGE = [&](int buf, int k0) {
        __builtin_amdgcn_global_load_lds(
            (const __attribute__((address_space(1))) uint32*)(Abase + (size_t)(m0 + ar0) * 512 + k0 * 2 + ac0),
            (__attribute__((address_space(3))) uint32*)(AsB + buf * 8192 + (wid * 2 + 0) * 1024), 16, 0, 0);
        __builtin_amdgcn_global_load_lds(
            (const __attribute__((address_space(1))) uint32*)(Abase + (size_t)(m0 + ar1) * 512 + k0 * 2 + ac1),
            (__attribute__((address_space(3))) uint32*)(AsB + buf * 8192 + (wid * 2 + 1) * 1024), 16, 0, 0);
        __builtin_amdgcn_global_load_lds(
            (const __attribute__((address_space(1))) uint32*)(Bbase + (size_t)(n0 + ar0) * 512 + k0 * 2 + ac0),
            (__attribute__((address_space(3))) uint32*)(BsB + buf * 8192 + (wid * 2 + 0) * 1024), 16, 0, 0);
        __builtin_amdgcn_global_load_lds(
            (const __attribute__((address_space(1))) uint32*)(Bbase + (size_t)(n0 + ar1) * 512 + k0 * 2 + ac1),
            (__attribute__((address_space(3))) uint32*)(BsB + buf * 8192 + (wid * 2 + 1) * 1024), 16, 0, 0);
    };

    STAGE(0, 0);
    __syncthreads();
    int cur = 0;
    for (int tt = 0; tt < 8; ++tt) {
        if (tt < 7) STAGE(cur ^ 1, (tt + 1) * 32);
        s16x8 af[4], bfv[4];
        #pragma unroll
        for (int m = 0; m < 4; ++m)
            af[m] = *(const s16x8*)(As[cur] + (size_t)(wr * 64 + m * 16 + (l & 15)) * 32 + (l >> 4) * 8);
        #pragma unroll
        for (int n = 0; n < 4; ++n)
            bfv[n] = *(const s16x8*)(Bs[cur] + (size_t)(wc * 64 + n * 16 + (l & 15)) * 32 + (l >> 4) * 8);
        #pragma unroll
        for (int m = 0; m < 4; ++m)
            #pragma unroll
            for (int n = 0; n < 4; ++n)
                acc[m][n] = __builtin_amdgcn_mfma_f32_16x16x32_bf16(af[m], bfv[n], acc[m][n], 0, 0, 0);
        __syncthreads();
        cur ^= 1;
    }

    const int mat = n0 >> 8;
    const int colBase = (n0 & 255) + wc * 64;
    const float* bias = g.b[mat];
    unsigned short* O = g.o[mat];
    #pragma unroll
    for (int n = 0; n < 4; ++n) {
        int col = colBase + n * 16 + (l & 15);
        float bv = bias[col];
        #pragma unroll
        for (int m = 0; m < 4; ++m) {
            int row0 = m0 + wr * 64 + m * 16 + (l >> 4) * 4;
            #pragma unroll
            for (int r = 0; r < 4; ++r) {
                int row = row0 + r;
                if (row < M)
                    O[(size_t)row * HCH + col] = f2bf(acc[m][n][r] + bv);
            }
        }
    }
}

// ---------------- classifier GEMM (fused relu + W2 dot) ----------------
__global__ __launch_bounds__(256) void k_cls(
    const unsigned short* __restrict__ A, const unsigned short* __restrict__ Bt,
    const float* __restrict__ b1, const float* __restrict__ W2,
    const float* __restrict__ b2, float* __restrict__ out, int M) {
    __shared__ __align__(16) unsigned short As[128 * 32];
    __shared__ __align__(16) unsigned short Bs[128 * 32];
    const int t = threadIdx.x, wid = t >> 6, l = t & 63;
    const int m0 = blockIdx.x * 128;
    const int wr = wid >> 1, wc = wid & 1;

    f32x4 acc[4][4];
    #pragma unroll
    for (int m = 0; m < 4; ++m)
        #pragma unroll
        for (int n = 0; n < 4; ++n) acc[m][n] = (f32x4)0.f;

    const int off0 = (wid * 2 + 0) * 1024 + l * 16;
    const int off1 = (wid * 2 + 1) * 1024 + l * 16;
    const int ar0 = off0 >> 6, ac0 = off0 & 63;
    const int ar1 = off1 >> 6, ac1 = off1 & 63;
    const char* Abase = (const char*)A;
    const char* Bbase = (const char*)Bt;
    char* AsB = (char*)As;
    char* BsB = (char*)Bs;

    for (int k0 = 0; k0 < 256; k0 += 32) {
        __builtin_amdgcn_global_load_lds(
            (const __attribute__((address_space(1))) uint32*)(Abase + (size_t)(m0 + ar0) * 512 + k0 * 2 + ac0),
            (__attribute__((address_space(3))) uint32*)(AsB + (wid * 2 + 0) * 1024), 16, 0, 0);
        __builtin_amdgcn_global_load_lds(
            (const __attribute__((address_space(1))) uint32*)(Abase + (size_t)(m0 + ar1) * 512 + k0 * 2 + ac1),
            (__attribute__((address_space(3))) uint32*)(AsB + (wid * 2 + 1) * 1024), 16, 0, 0);
        __builtin_amdgcn_global_load_lds(
            (const __attribute__((address_space(1))) uint32*)(Bbase + (size_t)(ar0)*512 + k0 * 2 + ac0),
            (__attribute__((address_space(3))) uint32*)(BsB + (wid * 2 + 0) * 1024), 16, 0, 0);
        __builtin_amdgcn_global_load_lds(
            (const __attribute__((address_space(1))) uint32*)(Bbase + (size_t)(ar1)*512 + k0 * 2 + ac1),
            (__attribute__((address_space(3))) uint32*)(BsB + (wid * 2 + 1) * 1024), 16, 0, 0);
        __syncthreads();

        s16x8 af[4], bfv[4];
        #pragma unroll
        for (int m = 0; m < 4; ++m)
            af[m] = *(const s16x8*)(As + (size_t)(wr * 64 + m * 16 + (l & 15)) * 32 + (l >> 4) * 8);
        #pragma unroll
        for (int n = 0; n < 4; ++n)
            bfv[n] = *(const s16x8*)(Bs + (size_t)(wc * 64 + n * 16 + (l & 15)) * 32 + (l >> 4) * 8);
        #pragma unroll
        for (int m = 0; m < 4; ++m)
            #pragma unroll
            for (int n = 0; n < 4; ++n)
                acc[m][n] = __builtin_amdgcn_mfma_f32_16x16x32_bf16(af[m], bfv[n], acc[m][n], 0, 0, 0);
        __syncthreads();
    }

    float w2v[4], bv[4];
    #pragma unroll
    for (int n = 0; n < 4; ++n) {
        int col = wc * 64 + n * 16 + (l & 15);
        w2v[n] = W2[col];
        bv[n] = b1[col];
    }
    float partv[16];
    #pragma unroll
    for (int m = 0; m < 4; ++m)
        #pragma unroll
        for (int r = 0; r < 4; ++r) {
            float pv = 0.f;
            #pragma unroll
            for (int n = 0; n < 4; ++n)
                pv = fmaf(fmaxf(acc[m][n][r] + bv[n], 0.f), w2v[n], pv);
            pv += __shfl_xor(pv, 1); pv += __shfl_xor(pv, 2);
            pv += __shfl_xor(pv, 4); pv += __shfl_xor(pv, 8);
            partv[m * 4 + r] = pv;
        }
    float* cbuf = (float*)As;
    if (wc == 0 && (l & 15) == 0) {
        #pragma unroll
        for (int m = 0; m < 4; ++m)
            #pragma unroll
            for (int r = 0; r < 4; ++r)
                cbuf[wr * 64 + m * 16 + (l >> 4) * 4 + r] = partv[m * 4 + r];
    }
    __syncthreads();
    if (wc == 1 && (l & 15) == 0) {
        float b2v = b2[0];
        #pragma unroll
        for (int m = 0; m < 4; ++m)
            #pragma unroll
            for (int r = 0; r < 4; ++r) {
                int rl = wr * 64 + m * 16 + (l >> 4) * 4 + r;
                int row = m0 + rl;
                if (row < M) out[row] = cbuf[rl] + partv[m * 4 + r] + b2v;
            }
    }
}

// ---------------- phase A: gather K only, compute w=exp(alpha), ssum, accE ----------------
__global__ __launch_bounds__(256) void k_alpha(
    const unsigned short* __restrict__ Q, const unsigned short* __restrict__ K,
    const int* __restrict__ off, const int2* __restrict__ csr,
    const float* __restrict__ We,
    float* __restrict__ wbuf, float* __restrict__ SS, float* __restrict__ AE,
    int nnodes) {
    int n = blockIdx.x * 8 + (threadIdx.x >> 5);
    if (n >= nnodes) return;
    int s = threadIdx.x & 31;
    size_t base = (size_t)n * HCH + s * 8;

    u16x8 qu = *(const u16x8*)(Q + base);
    float qf[8], wef[8];
    #pragma unroll
    for (int c = 0; c < 8; ++c) qf[c] = bf2f(qu[c]) * 0.125f;
    float4 we0 = *(const float4*)(We + s * 8);
    float4 we1 = *(const float4*)(We + s * 8 + 4);
    wef[0] = we0.x; wef[1] = we0.y; wef[2] = we0.z; wef[3] = we0.w;
    wef[4] = we1.x; wef[5] = we1.y; wef[6] = we1.z; wef[7] = we1.w;

    float p = 0.f;
    #pragma unroll
    for (int c = 0; c < 8; ++c) p = fmaf(qf[c], wef[c], p);
    p += __shfl_xor(p, 1); p += __shfl_xor(p, 2); p += __shfl_xor(p, 4);
    float qWe = p;

    float ssum = 0.f, accE = 0.f;
    int e0 = off[n], e1 = off[n + 1];
    const int laneoff = s * 8;
    const int h = s >> 3;
    const bool writer = (s & 7) == 0;
    for (int idx = e0; idx < e1; idx += 4) {
        u16x8 ku[4];
        float at[4];
        bool ok[4];
        #pragma unroll
        for (int j = 0; j < 4; ++j) {
            bool o = (idx + j) < e1;
            int2 ee = o ? csr[idx + j] : make_int2(0, 0);
            ok[j] = o;
            at[j] = __int_as_float(ee.y);
            ku[j] = *(const u16x8*)(K + ((size_t)ee.x << 8) + laneoff);
        }
        #pragma unroll
        for (int j = 0; j < 4; ++j) {
            float d = 0.f;
            #pragma unroll
            for (int c = 0; c < 8; ++c) d = fmaf(qf[c], bf2f(ku[j][c]), d);
            d += __shfl_xor(d, 1); d += __shfl_xor(d, 2); d += __shfl_xor(d, 4);
            float alpha = fmaf(at[j], qWe, d);
            float w = ok[j] ? __expf(fminf(alpha, 60.f)) : 0.f;
            ssum += w;
            accE = fmaf(w, at[j], accE);
            if (ok[j] && writer) wbuf[(size_t)(idx + j) * 4 + h] = w;
        }
    }
    if (writer) {
        SS[n * 4 + h] = ssum;
        AE[n * 4 + h] = accE;
    }
}

// ---------------- phase B: gather V only, weighted sum + epilogue ----------------
__global__ __launch_bounds__(256) void k_aggv(
    const unsigned short* __restrict__ V, const unsigned short* __restrict__ S,
    const int* __restrict__ off, const int2* __restrict__ csr,
    const float* __restrict__ wbuf, const float* __restrict__ SS,
    const float* __restrict__ AE, const float* __restrict__ We,
    unsigned short* __restrict__ Ho, int nnodes) {
    int n = blockIdx.x * 8 + (threadIdx.x >> 5);
    if (n >= nnodes) return;
    int s = threadIdx.x & 31;
    size_t base = (size_t)n * HCH + s * 8;
    const int laneoff = s * 8;
    const int h = s >> 3;

    float acc[8];
    #pragma unroll
    for (int c = 0; c < 8; ++c) acc[c] = 0.f;

    int e0 = off[n], e1 = off[n + 1];
    for (int idx = e0; idx < e1; idx += 4) {
        u16x8 vu[4];
        float w[4];
        #pragma unroll
        for (int j = 0; j < 4; ++j) {
            bool o = (idx + j) < e1;
            int2 ee = o ? csr[idx + j] : make_int2(0, 0);
            w[j] = o ? wbuf[(size_t)(idx + j) * 4 + h] : 0.f;
            vu[j] = *(const u16x8*)(V + ((size_t)ee.x << 8) + laneoff);
        }
        #pragma unroll
        for (int j = 0; j < 4; ++j) {
            #pragma unroll
            for (int c = 0; c < 8; ++c) acc[c] = fmaf(w[j], bf2f(vu[j][c]), acc[c]);
        }
    }

    float wef[8];
    float4 we0 = *(const float4*)(We + s * 8);
    float4 we1 = *(const float4*)(We + s * 8 + 4);
    wef[0] = we0.x; wef[1] = we0.y; wef[2] = we0.z; wef[3] = we0.w;
    wef[4] = we1.x; wef[5] = we1.y; wef[6] = we1.z; wef[7] = we1.w;

    float ssum = SS[n * 4 + h];
    float accE = AE[n * 4 + h];
    float inv = 1.f / (ssum + 1e-16f);
    u16x8 su = *(const u16x8*)(S + base);
    u16x8 o;
    #pragma unroll
    for (int c = 0; c < 8; ++c)
        o[c] = f2bf(fmaxf(fmaf(acc[c] + accE * wef[c], inv, bf2f(su[c])), 0.f));
    *(u16x8*)(Ho + base) = o;
}

extern "C" void kernel_launch(void* const* d_in, const int* in_sizes, int n_in,
                              void* d_out, int out_size, void* d_ws, size_t ws_size,
                              hipStream_t stream) {
    const float* x      = (const float*)d_in[0];
    const int*   ei     = (const int*)d_in[1];
    const float* eattr  = (const float*)d_in[2];
    const float* l0_Wq  = (const float*)d_in[3];
    const float* l0_bq  = (const float*)d_in[4];
    const float* l0_Wk  = (const float*)d_in[5];
    const float* l0_bk  = (const float*)d_in[6];
    const float* l0_Wv  = (const float*)d_in[7];
    const float* l0_bv  = (const float*)d_in[8];
    const float* l0_We  = (const float*)d_in[9];
    const float* l0_Wsk = (const float*)d_in[10];
    const float* l0_bsk = (const float*)d_in[11];
    const float* r_Wq   = (const float*)d_in[12];
    const float* r_bq   = (const float*)d_in[13];
    const float* r_Wk   = (const float*)d_in[14];
    const float* r_bk   = (const float*)d_in[15];
    const float* r_Wv   = (const float*)d_in[16];
    const float* r_bv   = (const float*)d_in[17];
    const float* r_We   = (const float*)d_in[18];
    const float* r_Wsk  = (const float*)d_in[19];
    const float* r_bsk  = (const float*)d_in[20];
    const float* cls_W1 = (const float*)d_in[21];
    const float* cls_b1 = (const float*)d_in[22];
    const float* cls_W2 = (const float*)d_in[23];
    const float* cls_b2 = (const float*)d_in[24];
    float* out = (float*)d_out;

    const int* src = ei;
    const int* dst = ei + NE;

    char* p = (char*)d_ws;
    auto alloc = [&](size_t bytes) {
        char* r = p;
        p += (bytes + 255) & ~(size_t)255;
        return r;
    };
    unsigned short* h  = (unsigned short*)alloc((size_t)MPAD * HCH * 2);
    unsigned short* Qb = (unsigned short*)alloc((size_t)NN * HCH * 2);
    unsigned short* Kb = (unsigned short*)alloc((size_t)NN * HCH * 2);
    unsigned short* Vb = (unsigned short*)alloc((size_t)NN * HCH * 2);
    unsigned short* Sb = (unsigned short*)alloc((size_t)NN * HCH * 2);
    unsigned short* Bt = (unsigned short*)alloc((size_t)2 * 1024 * 256 * 2);
    unsigned short* W1t= (unsigned short*)alloc((size_t)128 * 256 * 2);
    float* gram   = (float*)alloc(4 * 16 * 4);
    float* wbuf   = (float*)alloc((size_t)NE * 4 * 4);
    float* SSb    = (float*)alloc((size_t)NN * 4 * 4);
    float* AEb    = (float*)alloc((size_t)NN * 4 * 4);
    int* deg      = (int*)alloc((size_t)NN * 4);
    int* incl     = (int*)alloc((size_t)NN * 4);
    int* off      = (int*)alloc((size_t)(NN + 1) * 4);
    int* cur      = (int*)alloc((size_t)NN * 4);
    int* btot     = (int*)alloc(64 * 4);
    int2* csr     = (int2*)alloc((size_t)NE * 8);

    const int NB = (NN + 1023) / 1024;   // 49

    // ---- prep (pack + deg zero + gram), independent of CSR ----
    PackSrc ps;
    ps.w[0] = r_Wq;  ps.w[1] = r_Wk;  ps.w[2] = r_Wv;  ps.w[3] = r_Wsk;
    ps.w[4] = r_Wq + (size_t)HCH * HCH;  ps.w[5] = r_Wk + (size_t)HCH * HCH;
    ps.w[6] = r_Wv + (size_t)HCH * HCH;  ps.w[7] = r_Wsk + (size_t)HCH * HCH;
    ps.w[8] = cls_W1;
    k_prep<<<2177 + 196, 256, 0, stream>>>(ps, Bt, W1t, deg,
                                           l0_Wq, l0_bq, l0_Wk, l0_bk, l0_We, gram);

    // ---- CSR by dst ----
    k_hist<<<(NE + 255) / 256, 256, 0, stream>>>(dst, deg, NE);
    k_scan_a<<<NB, 1024, 0, stream>>>(deg, incl, btot, NN);
    k_scan_c<<<NB, 1024, 0, stream>>>(deg, incl, btot, off, cur, NN, NB);
    k_scatter<<<(NE + 255) / 256, 256, 0, stream>>>(src, dst, eattr, cur, csr, NE);

    // ---- layer 0 (closed-form rank-2 aggregation) ----
    k_agg0<<<(NN + 7) / 8, 256, 0, stream>>>(x, off, csr, gram,
                                             l0_Wv, l0_bv, l0_We, l0_Wsk, l0_bsk, h, NN);

    // ---- layers 1..2 ----
    const int mt = (NN + 127) / 128;  // 391
    const int at = (NN + 7) / 8;      // 6250
    for (int i = 0; i < 2; ++i) {
        const unsigned short* Bi = Bt + (size_t)i * 1024 * 256;
        GOut4 g;
        g.o[0] = Qb; g.b[0] = r_bq + (size_t)i * HCH;
        g.o[1] = Kb; g.b[1] = r_bk + (size_t)i * HCH;
        g.o[2] = Vb; g.b[2] = r_bv + (size_t)i * HCH;
        g.o[3] = Sb; g.b[3] = r_bsk + (size_t)i * HCH;
        k_mfma4<<<mt * 8, 256, 0, stream>>>(h, Bi, g, NN);
        k_alpha<<<at, 256, 0, stream>>>(Qb, Kb, off, csr, r_We + (size_t)i * HCH,
                                        wbuf, SSb, AEb, NN);
        k_aggv<<<at, 256, 0, stream>>>(Vb, Sb, off, csr, wbuf, SSb, AEb,
                                       r_We + (size_t)i * HCH, h, NN);
    }

    // ---- classifier ----
    k_cls<<<mt, 256, 0, stream>>>(h, W1t, cls_b1, cls_W2, cls_b2, out, NN);
}

// Round 9
// 463.957 us; speedup vs baseline: 1.1900x; 1.1900x over previous
//
#include <hip/hip_runtime.h>
#include <cstddef>

#define NN 50000
#define NE 800000
#define HCH 256     // H*C
#define MPAD 50048  // 391*128

typedef __attribute__((ext_vector_type(4))) float f32x4;
typedef __attribute__((ext_vector_type(8))) short s16x8;
typedef __attribute__((ext_vector_type(8))) unsigned short u16x8;
typedef unsigned int uint32;

__device__ inline float bf2f(unsigned short u) {
    return __uint_as_float(((unsigned int)u) << 16);
}
__device__ inline unsigned short f2bf(float f) {
    unsigned int x = __float_as_uint(f);
    x += 0x7FFFu + ((x >> 16) & 1u);   // round to nearest even
    return (unsigned short)(x >> 16);
}

// ---------------- CSR build ----------------
__global__ void k_hist(const int* __restrict__ dst, int* __restrict__ deg, int e) {
    int i = blockIdx.x * blockDim.x + threadIdx.x;
    if (i < e) atomicAdd(&deg[dst[i]], 1);
}

__global__ __launch_bounds__(1024) void k_scan_a(const int* __restrict__ deg,
                                                 int* __restrict__ incl,
                                                 int* __restrict__ btot, int n) {
    __shared__ int buf[1024];
    int t = threadIdx.x;
    int i = blockIdx.x * 1024 + t;
    int v = (i < n) ? deg[i] : 0;
    buf[t] = v;
    __syncthreads();
    #pragma unroll
    for (int s = 1; s < 1024; s <<= 1) {
        int tv = (t >= s) ? buf[t - s] : 0;
        __syncthreads();
        buf[t] += tv;
        __syncthreads();
    }
    if (i < n) incl[i] = buf[t];
    if (t == 1023) btot[blockIdx.x] = buf[1023];
}

__global__ __launch_bounds__(1024) void k_scan_c(const int* __restrict__ deg,
                                                 const int* __restrict__ incl,
                                                 const int* __restrict__ btot,
                                                 int* __restrict__ off,
                                                 int* __restrict__ cur, int n, int nb) {
    __shared__ int bsh;
    int t = threadIdx.x;
    if (t < 64) {
        int v = (t < nb && t < (int)blockIdx.x) ? btot[t] : 0;
        #pragma unroll
        for (int m = 1; m < 64; m <<= 1) v += __shfl_xor(v, m);
        if (t == 0) bsh = v;
    }
    __syncthreads();
    int bbase = bsh;
    int i = blockIdx.x * 1024 + t;
    if (i < n) {
        int inc = bbase + incl[i];
        off[i + 1] = inc;
        cur[i] = inc - deg[i];
    }
    if (i == 0) off[0] = 0;
}

__global__ void k_scatter(const int* __restrict__ src, const int* __restrict__ dst,
                          const float* __restrict__ attr, int* __restrict__ cur,
                          int2* __restrict__ csr, int e) {
    int i = blockIdx.x * blockDim.x + threadIdx.x;
    if (i < e) {
        int d = dst[i];
        int pos = atomicAdd(&cur[d], 1);
        csr[pos] = make_int2(src[i], __float_as_int(attr[i]));
    }
}

// ---------------- fused prep: weight pack + deg zero + layer-0 Gram ----------------
struct PackSrc { const float* w[9]; };
__global__ void k_prep(PackSrc ps, unsigned short* __restrict__ Bt,
                       unsigned short* __restrict__ W1t, int* __restrict__ deg,
                       const float* __restrict__ Wq, const float* __restrict__ bq,
                       const float* __restrict__ Wk, const float* __restrict__ bk,
                       const float* __restrict__ We, float* __restrict__ gram) {
    int b = blockIdx.x;
    if (b < 2176) {
        int i = b * 256 + threadIdx.x;
        if (i < 524288) {
            int mi = i >> 16;
            int elem = i & 65535;
            int n = elem >> 8, k = elem & 255;
            Bt[i] = f2bf(ps.w[mi][(size_t)k * 256 + n]);
        } else {
            int e = i - 524288;
            int n = e >> 8, k = e & 255;
            W1t[e] = f2bf(ps.w[8][(size_t)k * 128 + n]);
        }
    } else if (b < 2176 + 196) {
        int i = (b - 2176) * 256 + threadIdx.x;
        if (i < NN) deg[i] = 0;
    } else {
        int t = threadIdx.x;
        if (t < 48) {
            int h = t / 12, q = t % 12, i = q >> 2, j = q & 3;
            const float* a = (i < 2) ? Wq + i * HCH + h * 64 : bq + h * 64;
            const float* bb = (j == 0) ? Wk + h * 64
                            : (j == 1) ? Wk + HCH + h * 64
                            : (j == 2) ? bk + h * 64
                                       : We + h * 64;
            float s = 0.f;
            for (int c = 0; c < 64; ++c) s = fmaf(a[c], bb[c], s);
            gram[h * 16 + i * 4 + j] = s;
        }
    }
}

// ---------------- layer-0 fused aggregation (rank-2 closed form) ----------------
__global__ __launch_bounds__(256) void k_agg0(
    const float* __restrict__ x, const int* __restrict__ off,
    const int2* __restrict__ csr, const float* __restrict__ gram,
    const float* __restrict__ Wv, const float* __restrict__ bv,
    const float* __restrict__ We, const float* __restrict__ Wsk,
    const float* __restrict__ bsk,
    unsigned short* __restrict__ Ho, int nnodes) {
    int n = blockIdx.x * 8 + (threadIdx.x >> 5);
    if (n >= nnodes) return;
    int s = threadIdx.x & 31;
    float xd0 = x[n * 2], xd1 = x[n * 2 + 1];

    float t0[4], t1[4], t2[4], ta[4];
    #pragma unroll
    for (int h = 0; h < 4; ++h) {
        const float* g = gram + h * 16;
        t0[h] = (xd0 * g[0] + xd1 * g[4] + g[8])  * 0.125f;
        t1[h] = (xd0 * g[1] + xd1 * g[5] + g[9])  * 0.125f;
        t2[h] = (xd0 * g[2] + xd1 * g[6] + g[10]) * 0.125f;
        ta[h] = (xd0 * g[3] + xd1 * g[7] + g[11]) * 0.125f;
    }

    float S0[4] = {0,0,0,0}, S1[4] = {0,0,0,0}, S2[4] = {0,0,0,0}, SE[4] = {0,0,0,0};
    int e0 = off[n], e1 = off[n + 1];
    for (int e = e0 + s; e < e1; e += 32) {
        int2 ee = csr[e];
        float2 xs = ((const float2*)x)[ee.x];
        float attr = __int_as_float(ee.y);
        #pragma unroll
        for (int h = 0; h < 4; ++h) {
            float alpha = fmaf(t0[h], xs.x, fmaf(t1[h], xs.y, fmaf(ta[h], attr, t2[h])));
            float w = __expf(fminf(alpha, 60.f));
            S0[h] = fmaf(w, xs.x, S0[h]);
            S1[h] = fmaf(w, xs.y, S1[h]);
            S2[h] += w;
            SE[h] = fmaf(w, attr, SE[h]);
        }
    }
    #pragma unroll
    for (int m = 1; m < 32; m <<= 1) {
        #pragma unroll
        for (int h = 0; h < 4; ++h) {
            S0[h] += __shfl_xor(S0[h], m);
            S1[h] += __shfl_xor(S1[h], m);
            S2[h] += __shfl_xor(S2[h], m);
            SE[h] += __shfl_xor(SE[h], m);
        }
    }
    int hs = s >> 3;
    float inv = 1.f / (S2[hs] + 1e-16f);
    float s0 = S0[hs], s1 = S1[hs], s2 = S2[hs], se = SE[hs];
    int cbase = s * 8;
    u16x8 o;
    #pragma unroll
    for (int c = 0; c < 8; ++c) {
        int ch = cbase + c;
        float msg = (s0 * Wv[ch] + s1 * Wv[HCH + ch] + s2 * bv[ch] + se * We[ch]) * inv;
        float val = msg + xd0 * Wsk[ch] + xd1 * Wsk[HCH + ch] + bsk[ch];
        o[c] = f2bf(fmaxf(val, 0.f));
    }
    *(u16x8*)(Ho + (size_t)n * HCH + cbase) = o;
}

// ---------------- unified 4-matrix MFMA GEMM ----------------
// Swapped-operand MFMA: lane holds 4 CONSECUTIVE COLS of one row ->
// LDS-staged output tile -> full-line coalesced global stores.
struct GOut4 {
    unsigned short* o[4];
    const float* b[4];
};

__global__ __launch_bounds__(256) void k_mfma4(
    const unsigned short* __restrict__ A, const unsigned short* __restrict__ Bt,
    GOut4 g, int M) {
    __shared__ __align__(16) unsigned short lds[16384];   // 32 KB
    const int t = threadIdx.x, wid = t >> 6, l = t & 63;
    const int v = (blockIdx.x & 7) * 391 + (blockIdx.x >> 3);
    const int m0 = (v >> 3) * 128;
    const int n0 = (v & 7) * 128;
    const int wr = wid >> 1, wc = wid & 1;

    f32x4 acc[4][4];
    #pragma unroll
    for (int m = 0; m < 4; ++m)
        #pragma unroll
        for (int n = 0; n < 4; ++n) acc[m][n] = (f32x4)0.f;

    const int off0 = (wid * 2 + 0) * 1024 + l * 16;
    const int off1 = (wid * 2 + 1) * 1024 + l * 16;
    const int ar0 = off0 >> 6, ac0 = off0 & 63;
    const int ar1 = off1 >> 6, ac1 = off1 & 63;
    const char* Abase = (const char*)A;
    const char* Bbase = (const char*)Bt;
    char* LD = (char*)lds;

    auto STAGE = [&](int buf, int k0) {
        __builtin_amdgcn_global_load_lds(
            (const __attribute__((address_space(1))) uint32*)(Abase + (size_t)(m0 + ar0) * 512 + k0 * 2 + ac0),
            (__attribute__((address_space(3))) uint32*)(LD + buf * 8192 + (wid * 2 + 0) * 1024), 16, 0, 0);
        __builtin_amdgcn_global_load_lds(
            (const __attribute__((address_space(1))) uint32*)(Abase + (size_t)(m0 + ar1) * 512 + k0 * 2 + ac1),
            (__attribute__((address_space(3))) uint32*)(LD + buf * 8192 + (wid * 2 + 1) * 1024), 16, 0, 0);
        __builtin_amdgcn_global_load_lds(
            (const __attribute__((address_space(1))) uint32*)(Bbase + (size_t)(n0 + ar0) * 512 + k0 * 2 + ac0),
            (__attribute__((address_space(3))) uint32*)(LD + 16384 + buf * 8192 + (wid * 2 + 0) * 1024), 16, 0, 0);
        __builtin_amdgcn_global_load_lds(
            (const __attribute__((address_space(1))) uint32*)(Bbase + (size_t)(n0 + ar1) * 512 + k0 * 2 + ac1),
            (__attribute__((address_space(3))) uint32*)(LD + 16384 + buf * 8192 + (wid * 2 + 1) * 1024), 16, 0, 0);
    };

    STAGE(0, 0);
    __syncthreads();
    int cur = 0;
    for (int tt = 0; tt < 8; ++tt) {
        if (tt < 7) STAGE(cur ^ 1, (tt + 1) * 32);   // prefetch overlaps MFMA
        s16x8 af[4], bfv[4];
        const unsigned short* Asb = (const unsigned short*)(LD + cur * 8192);
        const unsigned short* Bsb = (const unsigned short*)(LD + 16384 + cur * 8192);
        #pragma unroll
        for (int m = 0; m < 4; ++m)
            af[m] = *(const s16x8*)(Asb + (size_t)(wr * 64 + m * 16 + (l & 15)) * 32 + (l >> 4) * 8);
        #pragma unroll
        for (int n = 0; n < 4; ++n)
            bfv[n] = *(const s16x8*)(Bsb + (size_t)(wc * 64 + n * 16 + (l & 15)) * 32 + (l >> 4) * 8);
        #pragma unroll
        for (int m = 0; m < 4; ++m)
            #pragma unroll
            for (int n = 0; n < 4; ++n)
                acc[m][n] = __builtin_amdgcn_mfma_f32_16x16x32_bf16(bfv[n], af[m], acc[m][n], 0, 0, 0);
        __syncthreads();
        cur ^= 1;
    }

    // ---- epilogue: stage 128x128 bf16 tile in LDS, then full-line stores ----
    const int mat = n0 >> 8;
    const float* bias = g.b[mat];
    unsigned short* O = g.o[mat];

    #pragma unroll
    for (int n = 0; n < 4; ++n) {
        int col0 = (n0 & 255) + wc * 64 + n * 16 + (l >> 4) * 4;
        float4 bv = *(const float4*)&bias[col0];
        #pragma unroll
        for (int m = 0; m < 4; ++m) {
            int row_l = wr * 64 + m * 16 + (l & 15);
            int colb = (wc * 64 + n * 16 + (l >> 4) * 4) * 2;   // byte offset in 256B row
            ushort4 pk;
            pk.x = f2bf(acc[m][n][0] + bv.x);
            pk.y = f2bf(acc[m][n][1] + bv.y);
            pk.z = f2bf(acc[m][n][2] + bv.z);
            pk.w = f2bf(acc[m][n][3] + bv.w);
            *(ushort4*)(LD + row_l * 256 + (colb ^ ((row_l & 15) << 4))) = pk;
        }
    }
    __syncthreads();
    #pragma unroll
    for (int pass = 0; pass < 8; ++pass) {
        int idx = pass * 4096 + t * 16;
        int row = idx >> 8;
        int colb = idx & 255;
        u16x8 val = *(const u16x8*)(LD + row * 256 + (colb ^ ((row & 15) << 4)));
        int grow = m0 + row;
        if (grow < M)
            *(u16x8*)((char*)O + (size_t)grow * 512 + (n0 & 255) * 2 + colb) = val;
    }
}

// ---------------- classifier GEMM (fused relu + W2 dot) ----------------
__global__ __launch_bounds__(256) void k_cls(
    const unsigned short* __restrict__ A, const unsigned short* __restrict__ Bt,
    const float* __restrict__ b1, const float* __restrict__ W2,
    const float* __restrict__ b2, float* __restrict__ out, int M) {
    __shared__ __align__(16) unsigned short As[128 * 32];
    __shared__ __align__(16) unsigned short Bs[128 * 32];
    const int t = threadIdx.x, wid = t >> 6, l = t & 63;
    const int m0 = blockIdx.x * 128;
    const int wr = wid >> 1, wc = wid & 1;

    f32x4 acc[4][4];
    #pragma unroll
    for (int m = 0; m < 4; ++m)
        #pragma unroll
        for (int n = 0; n < 4; ++n) acc[m][n] = (f32x4)0.f;

    const int off0 = (wid * 2 + 0) * 1024 + l * 16;
    const int off1 = (wid * 2 + 1) * 1024 + l * 16;
    const int ar0 = off0 >> 6, ac0 = off0 & 63;
    const int ar1 = off1 >> 6, ac1 = off1 & 63;
    const char* Abase = (const char*)A;
    const char* Bbase = (const char*)Bt;
    char* AsB = (char*)As;
    char* BsB = (char*)Bs;

    for (int k0 = 0; k0 < 256; k0 += 32) {
        __builtin_amdgcn_global_load_lds(
            (const __attribute__((address_space(1))) uint32*)(Abase + (size_t)(m0 + ar0) * 512 + k0 * 2 + ac0),
            (__attribute__((address_space(3))) uint32*)(AsB + (wid * 2 + 0) * 1024), 16, 0, 0);
        __builtin_amdgcn_global_load_lds(
            (const __attribute__((address_space(1))) uint32*)(Abase + (size_t)(m0 + ar1) * 512 + k0 * 2 + ac1),
            (__attribute__((address_space(3))) uint32*)(AsB + (wid * 2 + 1) * 1024), 16, 0, 0);
        __builtin_amdgcn_global_load_lds(
            (const __attribute__((address_space(1))) uint32*)(Bbase + (size_t)(ar0)*512 + k0 * 2 + ac0),
            (__attribute__((address_space(3))) uint32*)(BsB + (wid * 2 + 0) * 1024), 16, 0, 0);
        __builtin_amdgcn_global_load_lds(
            (const __attribute__((address_space(1))) uint32*)(Bbase + (size_t)(ar1)*512 + k0 * 2 + ac1),
            (__attribute__((address_space(3))) uint32*)(BsB + (wid * 2 + 1) * 1024), 16, 0, 0);
        __syncthreads();

        s16x8 af[4], bfv[4];
        #pragma unroll
        for (int m = 0; m < 4; ++m)
            af[m] = *(const s16x8*)(As + (size_t)(wr * 64 + m * 16 + (l & 15)) * 32 + (l >> 4) * 8);
        #pragma unroll
        for (int n = 0; n < 4; ++n)
            bfv[n] = *(const s16x8*)(Bs + (size_t)(wc * 64 + n * 16 + (l & 15)) * 32 + (l >> 4) * 8);
        #pragma unroll
        for (int m = 0; m < 4; ++m)
            #pragma unroll
            for (int n = 0; n < 4; ++n)
                acc[m][n] = __builtin_amdgcn_mfma_f32_16x16x32_bf16(af[m], bfv[n], acc[m][n], 0, 0, 0);
        __syncthreads();
    }

    float w2v[4], bv[4];
    #pragma unroll
    for (int n = 0; n < 4; ++n) {
        int col = wc * 64 + n * 16 + (l & 15);
        w2v[n] = W2[col];
        bv[n] = b1[col];
    }
    float partv[16];
    #pragma unroll
    for (int m = 0; m < 4; ++m)
        #pragma unroll
        for (int r = 0; r < 4; ++r) {
            float pv = 0.f;
            #pragma unroll
            for (int n = 0; n < 4; ++n)
                pv = fmaf(fmaxf(acc[m][n][r] + bv[n], 0.f), w2v[n], pv);
            pv += __shfl_xor(pv, 1); pv += __shfl_xor(pv, 2);
            pv += __shfl_xor(pv, 4); pv += __shfl_xor(pv, 8);
            partv[m * 4 + r] = pv;
        }
    float* cbuf = (float*)As;
    if (wc == 0 && (l & 15) == 0) {
        #pragma unroll
        for (int m = 0; m < 4; ++m)
            #pragma unroll
            for (int r = 0; r < 4; ++r)
                cbuf[wr * 64 + m * 16 + (l >> 4) * 4 + r] = partv[m * 4 + r];
    }
    __syncthreads();
    if (wc == 1 && (l & 15) == 0) {
        float b2v = b2[0];
        #pragma unroll
        for (int m = 0; m < 4; ++m)
            #pragma unroll
            for (int r = 0; r < 4; ++r) {
                int rl = wr * 64 + m * 16 + (l >> 4) * 4 + r;
                int row = m0 + rl;
                if (row < M) out[row] = cbuf[rl] + partv[m * 4 + r] + b2v;
            }
    }
}

// ---------------- fused gather + softmax + aggregate (layers 1..2) ----------------
__global__ __launch_bounds__(256) void k_agg(
    const unsigned short* __restrict__ Q, const unsigned short* __restrict__ K,
    const unsigned short* __restrict__ V, const unsigned short* __restrict__ S,
    const int* __restrict__ off, const int2* __restrict__ csr,
    const float* __restrict__ We,
    unsigned short* __restrict__ Ho, int nnodes) {
    int n = blockIdx.x * 8 + (threadIdx.x >> 5);
    if (n >= nnodes) return;
    int s = threadIdx.x & 31;
    size_t base = (size_t)n * HCH + s * 8;

    u16x8 qu = *(const u16x8*)(Q + base);
    float qf[8], wef[8];
    #pragma unroll
    for (int c = 0; c < 8; ++c) qf[c] = bf2f(qu[c]) * 0.125f;
    float4 we0 = *(const float4*)(We + s * 8);
    float4 we1 = *(const float4*)(We + s * 8 + 4);
    wef[0] = we0.x; wef[1] = we0.y; wef[2] = we0.z; wef[3] = we0.w;
    wef[4] = we1.x; wef[5] = we1.y; wef[6] = we1.z; wef[7] = we1.w;

    float p = 0.f;
    #pragma unroll
    for (int c = 0; c < 8; ++c) p = fmaf(qf[c], wef[c], p);
    p += __shfl_xor(p, 1); p += __shfl_xor(p, 2); p += __shfl_xor(p, 4);
    float qWe = p;

    float ssum = 0.f, accE = 0.f;
    float acc[8];
    #pragma unroll
    for (int c = 0; c < 8; ++c) acc[c] = 0.f;

    int e0 = off[n], e1 = off[n + 1];
    const int laneoff = s * 8;
    for (int idx = e0; idx < e1; idx += 4) {
        u16x8 ku[4], vu[4];
        float at[4];
        bool ok[4];
        #pragma unroll
        for (int j = 0; j < 4; ++j) {
            bool o = (idx + j) < e1;
            int2 ee = o ? csr[idx + j] : make_int2(0, 0);
            ok[j] = o;
            at[j] = __int_as_float(ee.y);
            size_t sb = ((size_t)ee.x << 8) + laneoff;
            ku[j] = *(const u16x8*)(K + sb);
            vu[j] = *(const u16x8*)(V + sb);
        }
        #pragma unroll
        for (int j = 0; j < 4; ++j) {
            float d = 0.f;
            #pragma unroll
            for (int c = 0; c < 8; ++c) d = fmaf(qf[c], bf2f(ku[j][c]), d);
            d += __shfl_xor(d, 1); d += __shfl_xor(d, 2); d += __shfl_xor(d, 4);
            float alpha = fmaf(at[j], qWe, d);
            float w = ok[j] ? __expf(fminf(alpha, 60.f)) : 0.f;
            ssum += w;
            accE = fmaf(w, at[j], accE);
            #pragma unroll
            for (int c = 0; c < 8; ++c) acc[c] = fmaf(w, bf2f(vu[j][c]), acc[c]);
        }
    }

    u16x8 su = *(const u16x8*)(S + base);
    float inv = 1.f / (ssum + 1e-16f);
    u16x8 o;
    #pragma unroll
    for (int c = 0; c < 8; ++c)
        o[c] = f2bf(fmaxf(fmaf(acc[c] + accE * wef[c], inv, bf2f(su[c])), 0.f));
    *(u16x8*)(Ho + base) = o;
}

extern "C" void kernel_launch(void* const* d_in, const int* in_sizes, int n_in,
                              void* d_out, int out_size, void* d_ws, size_t ws_size,
                              hipStream_t stream) {
    const float* x      = (const float*)d_in[0];
    const int*   ei     = (const int*)d_in[1];
    const float* eattr  = (const float*)d_in[2];
    const float* l0_Wq  = (const float*)d_in[3];
    const float* l0_bq  = (const float*)d_in[4];
    const float* l0_Wk  = (const float*)d_in[5];
    const float* l0_bk  = (const float*)d_in[6];
    const float* l0_Wv  = (const float*)d_in[7];
    const float* l0_bv  = (const float*)d_in[8];
    const float* l0_We  = (const float*)d_in[9];
    const float* l0_Wsk = (const float*)d_in[10];
    const float* l0_bsk = (const float*)d_in[11];
    const float* r_Wq   = (const float*)d_in[12];
    const float* r_bq   = (const float*)d_in[13];
    const float* r_Wk   = (const float*)d_in[14];
    const float* r_bk   = (const float*)d_in[15];
    const float* r_Wv   = (const float*)d_in[16];
    const float* r_bv   = (const float*)d_in[17];
    const float* r_We   = (const float*)d_in[18];
    const float* r_Wsk  = (const float*)d_in[19];
    const float* r_bsk  = (const float*)d_in[20];
    const float* cls_W1 = (const float*)d_in[21];
    const float* cls_b1 = (const float*)d_in[22];
    const float* cls_W2 = (const float*)d_in[23];
    const float* cls_b2 = (const float*)d_in[24];
    float* out = (float*)d_out;

    const int* src = ei;
    const int* dst = ei + NE;

    char* p = (char*)d_ws;
    auto alloc = [&](size_t bytes) {
        char* r = p;
        p += (bytes + 255) & ~(size_t)255;
        return r;
    };
    unsigned short* h  = (unsigned short*)alloc((size_t)MPAD * HCH * 2);
    unsigned short* Qb = (unsigned short*)alloc((size_t)NN * HCH * 2);
    unsigned short* Kb = (unsigned short*)alloc((size_t)NN * HCH * 2);
    unsigned short* Vb = (unsigned short*)alloc((size_t)NN * HCH * 2);
    unsigned short* Sb = (unsigned short*)alloc((size_t)NN * HCH * 2);
    unsigned short* Bt = (unsigned short*)alloc((size_t)2 * 1024 * 256 * 2);
    unsigned short* W1t= (unsigned short*)alloc((size_t)128 * 256 * 2);
    float* gram   = (float*)alloc(4 * 16 * 4);
    int* deg      = (int*)alloc((size_t)NN * 4);
    int* incl     = (int*)alloc((size_t)NN * 4);
    int* off      = (int*)alloc((size_t)(NN + 1) * 4);
    int* cur      = (int*)alloc((size_t)NN * 4);
    int* btot     = (int*)alloc(64 * 4);
    int2* csr     = (int2*)alloc((size_t)NE * 8);

    const int NB = (NN + 1023) / 1024;   // 49

    // ---- prep (pack + deg zero + gram), independent of CSR ----
    PackSrc ps;
    ps.w[0] = r_Wq;  ps.w[1] = r_Wk;  ps.w[2] = r_Wv;  ps.w[3] = r_Wsk;
    ps.w[4] = r_Wq + (size_t)HCH * HCH;  ps.w[5] = r_Wk + (size_t)HCH * HCH;
    ps.w[6] = r_Wv + (size_t)HCH * HCH;  ps.w[7] = r_Wsk + (size_t)HCH * HCH;
    ps.w[8] = cls_W1;
    k_prep<<<2177 + 196, 256, 0, stream>>>(ps, Bt, W1t, deg,
                                           l0_Wq, l0_bq, l0_Wk, l0_bk, l0_We, gram);

    // ---- CSR by dst ----
    k_hist<<<(NE + 255) / 256, 256, 0, stream>>>(dst, deg, NE);
    k_scan_a<<<NB, 1024, 0, stream>>>(deg, incl, btot, NN);
    k_scan_c<<<NB, 1024, 0, stream>>>(deg, incl, btot, off, cur, NN, NB);
    k_scatter<<<(NE + 255) / 256, 256, 0, stream>>>(src, dst, eattr, cur, csr, NE);

    // ---- layer 0 (closed-form rank-2 aggregation) ----
    k_agg0<<<(NN + 7) / 8, 256, 0, stream>>>(x, off, csr, gram,
                                             l0_Wv, l0_bv, l0_We, l0_Wsk, l0_bsk, h, NN);

    // ---- layers 1..2 ----
    const int mt = (NN + 127) / 128;  // 391
    for (int i = 0; i < 2; ++i) {
        const unsigned short* Bi = Bt + (size_t)i * 1024 * 256;
        GOut4 g;
        g.o[0] = Qb; g.b[0] = r_bq + (size_t)i * HCH;
        g.o[1] = Kb; g.b[1] = r_bk + (size_t)i * HCH;
        g.o[2] = Vb; g.b[2] = r_bv + (size_t)i * HCH;
        g.o[3] = Sb; g.b[3] = r_bsk + (size_t)i * HCH;
        k_mfma4<<<mt * 8, 256, 0, stream>>>(h, Bi, g, NN);
        k_agg<<<(NN + 7) / 8, 256, 0, stream>>>(Qb, Kb, Vb, Sb, off, csr,
                                                r_We + (size_t)i * HCH, h, NN);
    }

    // ---- classifier ----
    k_cls<<<mt, 256, 0, stream>>>(h, W1t, cls_b1, cls_W2, cls_b2, out, NN);
}